// Round 5
// baseline (309.666 us; speedup 1.0000x reference)
//
#include <hip/hip_runtime.h>
#include <hip/hip_bf16.h>

// DenoisingPotential: x_{t+1} = x_t + alpha * grad_phi(x_t), 10 iters.
// grad = (pacc - sum_k w_k y_k)/l,  y_k = P_k x,  w_k = exp(e_k + Pmu_k.x - 0.5 x.y_k)
//
// R8: model that fits R5/R6/R7: the wall is LDS read BW (every wave re-reads
// 8KB of P per k -> scales with wave count, R7 saturated at ~1880 cyc/round)
// PLUS per-k barrier lockstep (chain of k can't overlap k+1 in-wave).
// Fix: (a) 32 pts/wave (amortize A-reads; halves LDS demand per point),
// (b) TWO k's per barrier step: pair-wise double-buffered staging (2x16KB),
// two independent MFMA->dot->exp->accY chains interleave inside one barrier
// interval. Barriers/iter 32 -> 16. launch_bounds(256,2) -> 256-VGPR budget
// for the pair state (occupancy is LDS-capped at 2 blocks/CU anyway).

typedef __attribute__((ext_vector_type(4))) float f32x4;
typedef __attribute__((ext_vector_type(8))) short bf16x8;  // 8 bf16 = 4 VGPRs

#define KC 32
#define NITER 10
#define XROW 72        // bf16 elems per point-row in xs staging (pad vs 64)
#define WT_PITCH 40    // bf16 pitch of weight stash (pad vs 32)
#define PW_BYTES 7168  // per-wave: xsw(4608, aliased by pmxw 4096) + wtw(2560)
#define PPAIR 16384    // one k-PAIR's P fragments (2 x 64x64 bf16, contiguous)
// LDS total: 4*7168 + 2*16384 = 61440 B -> 2 blocks/CU

static __device__ __forceinline__ unsigned pk_bf16(float a, float b) {
  __hip_bfloat16 ha = __float2bfloat16(a), hb = __float2bfloat16(b);
  unsigned short ua = *(unsigned short*)&ha, ub = *(unsigned short*)&hb;
  return (unsigned)ua | ((unsigned)ub << 16);
}

// butterfly sum with lane^16: permlane16_swap is pure VALU (sum of the two
// outputs = x[l] + x[l^16] in every lane)
static __device__ __forceinline__ float red16(float x) {
#if __has_builtin(__builtin_amdgcn_permlane16_swap)
  int xi = __float_as_int(x);
  auto pr = __builtin_amdgcn_permlane16_swap(xi, xi, false, false);
  return __int_as_float(pr[0]) + __int_as_float(pr[1]);
#else
  int v = __builtin_amdgcn_ds_swizzle(__float_as_int(x), 0x401F);
  return x + __int_as_float(v);
#endif
}
// butterfly sum with lane^32 (VALU permlane32_swap)
static __device__ __forceinline__ float red32(float x) {
  int xi = __float_as_int(x);
  auto pr = __builtin_amdgcn_permlane32_swap(xi, xi, false, false);
  return __int_as_float(pr[0]) + __int_as_float(pr[1]);
}

// async global->LDS, 16B per lane; ldst is wave-uniform base (HW adds lane*16),
// gsrc is the per-lane source address.
static __device__ __forceinline__ void stage16(const void* gsrc, void* ldst) {
  __builtin_amdgcn_global_load_lds(
      (const __attribute__((address_space(1))) unsigned int*)gsrc,
      (__attribute__((address_space(3))) unsigned int*)ldst, 16, 0, 0);
}

// ---------------- precompute 1: per-k P = A^T A, Pmu, e, swizzled P ----------
__global__ void precompute1(const float* __restrict__ A, const float* __restrict__ mu,
                            const float* __restrict__ c,
                            float* __restrict__ Pmu_g, float* __restrict__ e_g,
                            __hip_bfloat16* __restrict__ Psw) {
  __shared__ float As[64 * 64];
  __shared__ float Pk[64 * 64];
  const int k = blockIdx.x, tid = threadIdx.x;
  const float* Ak = A + k * 4096;
  for (int idx = tid; idx < 1024; idx += 256)
    *(f32x4*)&As[idx * 4] = *(const f32x4*)&Ak[idx * 4];
  __syncthreads();

  // thread -> row i = tid>>2, col strip lg*16..lg*16+15
  const int i = tid >> 2, lg = tid & 3;
  float acc[16] = {};
  for (int j = 0; j < 64; ++j) {
    float ai = As[j * 64 + i];  // broadcast within quad
    const f32x4* row = (const f32x4*)&As[j * 64 + lg * 16];  // broadcast across i
#pragma unroll
    for (int g = 0; g < 4; ++g) {
      f32x4 v = row[g];
#pragma unroll
      for (int r = 0; r < 4; ++r) acc[g * 4 + r] += ai * v[r];
    }
  }
#pragma unroll
  for (int g = 0; g < 4; ++g)
#pragma unroll
    for (int r = 0; r < 4; ++r) Pk[i * 64 + lg * 16 + g * 4 + r] = acc[g * 4 + r];
  __syncthreads();

  if (tid < 64) {
    // Pmu[i] = sum_l P[l][i]*mu[l]  (P symmetric; transposed read = stride-1)
    float s = 0.f;
    for (int l = 0; l < 64; ++l) s += Pk[l * 64 + tid] * mu[k * 64 + l];
    Pmu_g[k * 64 + tid] = s;
    float v = mu[k * 64 + tid] * s;
#pragma unroll
    for (int off = 1; off < 64; off <<= 1) v += __shfl_xor(v, off, 64);
    if (tid == 0) e_g[k] = c[k] - 0.5f * v;
  }

  // A-frag order for the main GEMM: flat idx = f*512 + lane*8 + j,
  // f=(mt,s): val = P[dim_in = s*32 + qq*8 + j][dim_out = mt*16 + l4]
  unsigned* Psw32 = (unsigned*)(Psw + k * 4096);
  for (int idx2 = tid; idx2 < 2048; idx2 += 256) {
    int idx = idx2 << 1;  // even j
    int f = idx >> 9, ln = (idx >> 3) & 63, j = idx & 7;
    int mt = f >> 1, s = f & 1, qq = ln >> 4, l4 = ln & 15;
    int col = mt * 16 + l4, rb = s * 32 + qq * 8 + j;
    Psw32[idx2] = pk_bf16(Pk[rb * 64 + col], Pk[(rb + 1) * 64 + col]);
  }
}

// ---------------- precompute 2: Pmu fragment swizzles -----------------------
__global__ void precompute2(const float* __restrict__ Pmu_g,
                            __hip_bfloat16* __restrict__ PmuA,
                            __hip_bfloat16* __restrict__ PmuB) {
  const int tid = threadIdx.x;
  // PmuA (pmx GEMM A-operand): A[m=cluster][kk=dim]; frag f=(mtc,s)
  for (int idx = tid; idx < 2048; idx += 256) {
    int f = idx >> 9, lane = (idx >> 3) & 63, j = idx & 7;
    int mtc = f >> 1, s = f & 1, qq = lane >> 4, l4 = lane & 15;
    PmuA[idx] = __float2bfloat16(Pmu_g[(mtc * 16 + l4) * 64 + s * 32 + qq * 8 + j]);
  }
  // PmuB (pacc GEMM A-operand): A[m=dim][kk=cluster]; frag f=mtd (K=32, 1 step)
  for (int idx = tid; idx < 2048; idx += 256) {
    int f = idx >> 9, lane = (idx >> 3) & 63, j = idx & 7;
    int qq = lane >> 4, l4 = lane & 15;
    PmuB[idx] = __float2bfloat16(Pmu_g[(qq * 8 + j) * 64 + f * 16 + l4]);
  }
}

// ---------------- main kernel ----------------------------------------------
// 256 thr (4 waves), 32 pts/wave, grid 512 (2 blocks/CU, LDS-capped).
// P staged per k-PAIR into double-buffered LDS (wave w stages frags 4w..4w+3
// of 16); ONE barrier per pair; the two k-chains interleave inside.
__launch_bounds__(256, 2)
__global__ void denoise_main(const float* __restrict__ x_in,
                             const float* __restrict__ e_g,
                             const float* __restrict__ alpha_g,
                             const __hip_bfloat16* __restrict__ Psw,
                             const __hip_bfloat16* __restrict__ PmuA,
                             const __hip_bfloat16* __restrict__ PmuB,
                             float* __restrict__ out) {
  __shared__ __attribute__((aligned(16))) char scratch[4 * PW_BYTES + 2 * PPAIR];  // 60 KB

  const int tid = threadIdx.x;
  const int wave = tid >> 6, lane = tid & 63;
  const int q = lane >> 4, l4 = lane & 15;
  const int base_pt = blockIdx.x * 128 + wave * 32;
  const float alpha = alpha_g[0];

  char* pw = scratch + wave * PW_BYTES;
  __hip_bfloat16* xsw = (__hip_bfloat16*)pw;           // [32][XROW] bf16 staging
  float* pmxw = (float*)pw;                            // [32][32] f32 (xsw dead)
  __hip_bfloat16* wtw = (__hip_bfloat16*)(pw + 4608);  // [32][WT_PITCH] bf16
  char* pstg = scratch + 4 * PW_BYTES;                 // [2][PPAIR] pair bufs

  const char* PswB = (const char*)Psw;        // pair p = 16384 B contiguous
  const bf16x8* PmuAF = (const bf16x8*)PmuA;  // frag idx = f*64 + lane
  const bf16x8* PmuBF = (const bf16x8*)PmuB;

  // x master, C-layout: xm[mt][nt][r] = x[dim = mt*16+q*4+r][pt = nt*16+l4]
  f32x4 xm[4][2];
#pragma unroll
  for (int mt = 0; mt < 4; ++mt)
#pragma unroll
    for (int nt = 0; nt < 2; ++nt)
      xm[mt][nt] = *(const f32x4*)&x_in[(base_pt + nt * 16 + l4) * 64 + mt * 16 + q * 4];

  // e for pmx spill: cluster row mtc*16 + q*4 + r  ->  ev[mtc][r]
  f32x4 ev[2];
#pragma unroll
  for (int mtc = 0; mtc < 2; ++mtc) ev[mtc] = *(const f32x4*)&e_g[mtc * 16 + q * 4];

  const f32x4 Z4 = {0.f, 0.f, 0.f, 0.f};
  const int fb = 4 * wave;  // this wave's 4 staging fragments (of 16 per pair)

#pragma unroll 1
  for (int it = 0; it < NITER; ++it) {
    // ---- issue staging of pair 0 into buf0 early (hides under pmx phase) ---
#pragma unroll
    for (int i = 0; i < 4; ++i)
      stage16(PswB + (fb + i) * 1024 + lane * 16, pstg + (fb + i) * 1024);

    // ---- stage x (bf16) into wave-private rows [pt][dim], XROW-padded ----
#pragma unroll
    for (int mt = 0; mt < 4; ++mt)
#pragma unroll
      for (int nt = 0; nt < 2; ++nt) {
        uint2 v;
        v.x = pk_bf16(xm[mt][nt][0], xm[mt][nt][1]);
        v.y = pk_bf16(xm[mt][nt][2], xm[mt][nt][3]);
        *(uint2*)&xsw[(nt * 16 + l4) * XROW + mt * 16 + q * 4] = v;
      }

    // ---- B-frags of x: B[kk=dim=s*32+q*8+j][n=pt=l4] (constant over k) ----
    bf16x8 bx[2][2];
#pragma unroll
    for (int s = 0; s < 2; ++s)
#pragma unroll
      for (int nt = 0; nt < 2; ++nt)
        bx[s][nt] = *(const bf16x8*)&xsw[(nt * 16 + l4) * XROW + s * 32 + q * 8];

    // ---- pmx GEMM: pmx[cluster][pt] = sum_dim Pmu[cluster][dim]*x[dim][pt] ----
    f32x4 pmx[2][2];
#pragma unroll
    for (int mtc = 0; mtc < 2; ++mtc)
#pragma unroll
      for (int nt = 0; nt < 2; ++nt) {
        f32x4 acc = Z4;
#pragma unroll
        for (int s = 0; s < 2; ++s) {
          bf16x8 a = PmuAF[(mtc * 2 + s) * 64 + lane];
          acc = __builtin_amdgcn_mfma_f32_16x16x32_bf16(a, bx[s][nt], acc, 0, 0, 0);
        }
        pmx[mtc][nt] = acc;
      }
    // spill pmx + e (folded) to wave-private LDS [cluster32][pt32] f32
#pragma unroll
    for (int mtc = 0; mtc < 2; ++mtc)
#pragma unroll
      for (int nt = 0; nt < 2; ++nt)
#pragma unroll
        for (int r = 0; r < 4; ++r)
          pmxw[(mtc * 16 + q * 4 + r) * 32 + nt * 16 + l4] = pmx[mtc][nt][r] + ev[mtc][r];

    f32x4 accY[4][2];
#pragma unroll
    for (int mt = 0; mt < 4; ++mt)
#pragma unroll
      for (int nt = 0; nt < 2; ++nt) accY[mt][nt] = Z4;
    float lsum0 = 0.f, lsum1 = 0.f;

    __syncthreads();  // full vmcnt drain: pair-0 staged & visible to all waves

    // ---- pair-loop: 2 k's per barrier, double-buffered staging ----
#pragma unroll 2
    for (int kp = 0; kp < KC / 2; ++kp) {
      const int cur = kp & 1;
      if (kp < KC / 2 - 1) {  // issue staging of pair kp+1 into other buffer
        const char* ps = PswB + (kp + 1) * PPAIR;
        char* pd = pstg + (cur ^ 1) * PPAIR;
#pragma unroll
        for (int i = 0; i < 4; ++i)
          stage16(ps + (fb + i) * 1024 + lane * 16, pd + (fb + i) * 1024);
      }

      // fragments for both k's of the pair from staged LDS
      const char* pc = pstg + cur * PPAIR;
      bf16x8 a0[4][2], a1[4][2];
#pragma unroll
      for (int mt = 0; mt < 4; ++mt)
#pragma unroll
        for (int s = 0; s < 2; ++s) {
          a0[mt][s] = *(const bf16x8*)(pc + (mt * 2 + s) * 1024 + lane * 16);
          a1[mt][s] = *(const bf16x8*)(pc + 8192 + (mt * 2 + s) * 1024 + lane * 16);
        }

      // y = P x for both k's (independent MFMA chains)
      f32x4 y0[4][2], y1[4][2];
#pragma unroll
      for (int mt = 0; mt < 4; ++mt)
#pragma unroll
        for (int nt = 0; nt < 2; ++nt) {
          f32x4 acc = Z4;
          acc = __builtin_amdgcn_mfma_f32_16x16x32_bf16(a0[mt][0], bx[0][nt], acc, 0, 0, 0);
          acc = __builtin_amdgcn_mfma_f32_16x16x32_bf16(a0[mt][1], bx[1][nt], acc, 0, 0, 0);
          y0[mt][nt] = acc;
          f32x4 acc1 = Z4;
          acc1 = __builtin_amdgcn_mfma_f32_16x16x32_bf16(a1[mt][0], bx[0][nt], acc1, 0, 0, 0);
          acc1 = __builtin_amdgcn_mfma_f32_16x16x32_bf16(a1[mt][1], bx[1][nt], acc1, 0, 0, 0);
          y1[mt][nt] = acc1;
        }

      // dots for both k's (packed fp32 FMA; two independent chains)
      f32x4 d00 = xm[0][0] * y0[0][0];
      f32x4 d01 = xm[0][1] * y0[0][1];
      f32x4 d10 = xm[0][0] * y1[0][0];
      f32x4 d11 = xm[0][1] * y1[0][1];
#pragma unroll
      for (int mt = 1; mt < 4; ++mt) {
        d00 += xm[mt][0] * y0[mt][0];
        d01 += xm[mt][1] * y0[mt][1];
        d10 += xm[mt][0] * y1[mt][0];
        d11 += xm[mt][1] * y1[mt][1];
      }
      float xy00 = red32(red16((d00[0] + d00[1]) + (d00[2] + d00[3])));
      float xy01 = red32(red16((d01[0] + d01[1]) + (d01[2] + d01[3])));
      float xy10 = red32(red16((d10[0] + d10[1]) + (d10[2] + d10[3])));
      float xy11 = red32(red16((d11[0] + d11[1]) + (d11[2] + d11[3])));

      const int k0 = 2 * kp, k1 = 2 * kp + 1;
      const float w00 = __expf(pmxw[k0 * 32 + l4] - 0.5f * xy00);
      const float w01 = __expf(pmxw[k0 * 32 + 16 + l4] - 0.5f * xy01);
      const float w10 = __expf(pmxw[k1 * 32 + l4] - 0.5f * xy10);
      const float w11 = __expf(pmxw[k1 * 32 + 16 + l4] - 0.5f * xy11);
      lsum0 += w00 + w10;
      lsum1 += w01 + w11;
      if (q == 0) {
        wtw[l4 * WT_PITCH + k0] = __float2bfloat16(w00);
        wtw[(16 + l4) * WT_PITCH + k0] = __float2bfloat16(w01);
        wtw[l4 * WT_PITCH + k1] = __float2bfloat16(w10);
        wtw[(16 + l4) * WT_PITCH + k1] = __float2bfloat16(w11);
      }
#pragma unroll
      for (int mt = 0; mt < 4; ++mt) {
        accY[mt][0] += w00 * y0[mt][0];
        accY[mt][1] += w01 * y0[mt][1];
        accY[mt][0] += w10 * y1[mt][0];
        accY[mt][1] += w11 * y1[mt][1];
      }

      // barrier: all waves done reading buf[cur]; implicit full-vmcnt drain
      // makes every wave's staged next pair visible
      __syncthreads();
    }

    // ---- pacc[dim][pt] = sum_k Pmu[k][dim] * wt[k][pt]  (one K=32 GEMM) ----
    bf16x8 wtf[2];
#pragma unroll
    for (int nt = 0; nt < 2; ++nt)
      wtf[nt] = *(const bf16x8*)&wtw[(nt * 16 + l4) * WT_PITCH + q * 8];
    f32x4 pacc[4][2];
#pragma unroll
    for (int mt = 0; mt < 4; ++mt) {
      bf16x8 a = PmuBF[mt * 64 + lane];
      pacc[mt][0] = __builtin_amdgcn_mfma_f32_16x16x32_bf16(a, wtf[0], Z4, 0, 0, 0);
      pacc[mt][1] = __builtin_amdgcn_mfma_f32_16x16x32_bf16(a, wtf[1], Z4, 0, 0, 0);
    }

    // ---- x += (alpha/l) * (pacc - accY) ----
    const float c0 = alpha / lsum0;
    const float c1 = alpha / lsum1;
#pragma unroll
    for (int mt = 0; mt < 4; ++mt) {
      xm[mt][0] += c0 * (pacc[mt][0] - accY[mt][0]);
      xm[mt][1] += c1 * (pacc[mt][1] - accY[mt][1]);
    }
  }  // iterations

  // ---- direct f32x4 stores: 64B-contiguous per quad-row, fully in-bounds ---
#pragma unroll
  for (int mt = 0; mt < 4; ++mt)
#pragma unroll
    for (int nt = 0; nt < 2; ++nt)
      *(f32x4*)&out[(base_pt + nt * 16 + l4) * 64 + mt * 16 + q * 4] = xm[mt][nt];
}

extern "C" void kernel_launch(void* const* d_in, const int* in_sizes, int n_in,
                              void* d_out, int out_size, void* d_ws, size_t ws_size,
                              hipStream_t stream) {
  (void)in_sizes; (void)n_in; (void)out_size; (void)ws_size;
  const float* x = (const float*)d_in[0];
  const float* c = (const float*)d_in[1];
  const float* mu = (const float*)d_in[2];
  const float* A = (const float*)d_in[3];
  const float* alpha = (const float*)d_in[4];
  float* out = (float*)d_out;

  char* ws = (char*)d_ws;
  float* Pmu_g = (float*)(ws);                           // 8192 B
  float* e_g = (float*)(ws + 8192);                      // 128 B (pad to 256)
  __hip_bfloat16* PmuA = (__hip_bfloat16*)(ws + 8448);   // 4096 B
  __hip_bfloat16* PmuB = (__hip_bfloat16*)(ws + 12544);  // 4096 B
  __hip_bfloat16* Psw = (__hip_bfloat16*)(ws + 16640);   // 262144 B

  precompute1<<<32, 256, 0, stream>>>(A, mu, c, Pmu_g, e_g, Psw);
  precompute2<<<1, 256, 0, stream>>>(Pmu_g, PmuA, PmuB);
  denoise_main<<<512, 256, 0, stream>>>(x, e_g, alpha, Psw, PmuA, PmuB, out);
}

// Round 6
// 283.883 us; speedup vs baseline: 1.0908x; 1.0908x over previous
//
#include <hip/hip_runtime.h>
#include <hip/hip_bf16.h>

// DenoisingPotential: x_{t+1} = x_t + alpha * grad_phi(x_t), 10 iters.
// grad = (pacc - sum_k w_k y_k)/l,  y_k = P_k x,  w_k = exp(e_k + Pmu_k.x - 0.5 x.y_k)
//
// R9: R5 structure (barrier-free, wave-private, register-dbuf P from L2 --
// the best measured variant; all barrier/occupancy/pairing variants R6-R8
// were null or worse). Single change: MFMA emission order. R5 emitted each
// (mt,nt) tile as a DEPENDENT pair acc=mfma(s0); acc=mfma(s1,acc) -- in-order
// wave issue stalls ~MFMA-latency per pair and blocks the 7 independent pairs
// queued behind it (measured effective ~17.6 cyc/MFMA vs ~5 peak). Now: all
// 8 independent s=0 MFMAs issue first, then the 8 s=1 MFMAs (each sees its
// s=0 result ~8 MFMA issues later -> latency hidden). Same for pmx GEMM.
// Zero register cost (y[][] is the accumulator either way).

typedef __attribute__((ext_vector_type(4))) float f32x4;
typedef __attribute__((ext_vector_type(8))) short bf16x8;  // 8 bf16 = 4 VGPRs

#define KC 32
#define NITER 10
#define XROW 72        // bf16 elems per point-row in xs staging (pad vs 64)
#define WT_PITCH 40    // bf16 pitch of weight stash (pad vs 32)
#define PW_BYTES 7168  // per-wave: xsw(4608, aliased by pmxw 4096) + wtw(2560)
// LDS total: 4 * 7168 = 28672 B

static __device__ __forceinline__ unsigned pk_bf16(float a, float b) {
  __hip_bfloat16 ha = __float2bfloat16(a), hb = __float2bfloat16(b);
  unsigned short ua = *(unsigned short*)&ha, ub = *(unsigned short*)&hb;
  return (unsigned)ua | ((unsigned)ub << 16);
}

// butterfly sum with lane^16: permlane16_swap is pure VALU (sum of the two
// outputs = x[l] + x[l^16] in every lane)
static __device__ __forceinline__ float red16(float x) {
#if __has_builtin(__builtin_amdgcn_permlane16_swap)
  int xi = __float_as_int(x);
  auto pr = __builtin_amdgcn_permlane16_swap(xi, xi, false, false);
  return __int_as_float(pr[0]) + __int_as_float(pr[1]);
#else
  int v = __builtin_amdgcn_ds_swizzle(__float_as_int(x), 0x401F);
  return x + __int_as_float(v);
#endif
}
// butterfly sum with lane^32 (VALU permlane32_swap)
static __device__ __forceinline__ float red32(float x) {
  int xi = __float_as_int(x);
  auto pr = __builtin_amdgcn_permlane32_swap(xi, xi, false, false);
  return __int_as_float(pr[0]) + __int_as_float(pr[1]);
}

// ---------------- precompute 1: per-k P = A^T A, Pmu, e, swizzled P ----------
__global__ void precompute1(const float* __restrict__ A, const float* __restrict__ mu,
                            const float* __restrict__ c,
                            float* __restrict__ Pmu_g, float* __restrict__ e_g,
                            __hip_bfloat16* __restrict__ Psw) {
  __shared__ float As[64 * 64];
  __shared__ float Pk[64 * 64];
  const int k = blockIdx.x, tid = threadIdx.x;
  const float* Ak = A + k * 4096;
  for (int idx = tid; idx < 1024; idx += 256)
    *(f32x4*)&As[idx * 4] = *(const f32x4*)&Ak[idx * 4];
  __syncthreads();

  // thread -> row i = tid>>2, col strip lg*16..lg*16+15
  const int i = tid >> 2, lg = tid & 3;
  float acc[16] = {};
  for (int j = 0; j < 64; ++j) {
    float ai = As[j * 64 + i];  // broadcast within quad
    const f32x4* row = (const f32x4*)&As[j * 64 + lg * 16];  // broadcast across i
#pragma unroll
    for (int g = 0; g < 4; ++g) {
      f32x4 v = row[g];
#pragma unroll
      for (int r = 0; r < 4; ++r) acc[g * 4 + r] += ai * v[r];
    }
  }
#pragma unroll
  for (int g = 0; g < 4; ++g)
#pragma unroll
    for (int r = 0; r < 4; ++r) Pk[i * 64 + lg * 16 + g * 4 + r] = acc[g * 4 + r];
  __syncthreads();

  if (tid < 64) {
    // Pmu[i] = sum_l P[l][i]*mu[l]  (P symmetric; transposed read = stride-1)
    float s = 0.f;
    for (int l = 0; l < 64; ++l) s += Pk[l * 64 + tid] * mu[k * 64 + l];
    Pmu_g[k * 64 + tid] = s;
    float v = mu[k * 64 + tid] * s;
#pragma unroll
    for (int off = 1; off < 64; off <<= 1) v += __shfl_xor(v, off, 64);
    if (tid == 0) e_g[k] = c[k] - 0.5f * v;
  }

  // A-frag order for the main GEMM: flat idx = f*512 + lane*8 + j,
  // f=(mt,s): val = P[dim_in = s*32 + qq*8 + j][dim_out = mt*16 + l4]
  unsigned* Psw32 = (unsigned*)(Psw + k * 4096);
  for (int idx2 = tid; idx2 < 2048; idx2 += 256) {
    int idx = idx2 << 1;  // even j
    int f = idx >> 9, ln = (idx >> 3) & 63, j = idx & 7;
    int mt = f >> 1, s = f & 1, qq = ln >> 4, l4 = ln & 15;
    int col = mt * 16 + l4, rb = s * 32 + qq * 8 + j;
    Psw32[idx2] = pk_bf16(Pk[rb * 64 + col], Pk[(rb + 1) * 64 + col]);
  }
}

// ---------------- precompute 2: Pmu fragment swizzles -----------------------
__global__ void precompute2(const float* __restrict__ Pmu_g,
                            __hip_bfloat16* __restrict__ PmuA,
                            __hip_bfloat16* __restrict__ PmuB) {
  const int tid = threadIdx.x;
  // PmuA (pmx GEMM A-operand): A[m=cluster][kk=dim]; frag f=(mtc,s)
  for (int idx = tid; idx < 2048; idx += 256) {
    int f = idx >> 9, lane = (idx >> 3) & 63, j = idx & 7;
    int mtc = f >> 1, s = f & 1, qq = lane >> 4, l4 = lane & 15;
    PmuA[idx] = __float2bfloat16(Pmu_g[(mtc * 16 + l4) * 64 + s * 32 + qq * 8 + j]);
  }
  // PmuB (pacc GEMM A-operand): A[m=dim][kk=cluster]; frag f=mtd (K=32, 1 step)
  for (int idx = tid; idx < 2048; idx += 256) {
    int f = idx >> 9, lane = (idx >> 3) & 63, j = idx & 7;
    int qq = lane >> 4, l4 = lane & 15;
    PmuB[idx] = __float2bfloat16(Pmu_g[(qq * 8 + j) * 64 + f * 16 + l4]);
  }
}

// ---------------- main kernel ----------------------------------------------
// 256 thr (4 waves), 32 pts/wave, grid 512. NO __syncthreads anywhere; all
// LDS use is wave-private scratch. P comes via register double-buffer.
__launch_bounds__(256, 2)
__global__ void denoise_main(const float* __restrict__ x_in,
                             const float* __restrict__ e_g,
                             const float* __restrict__ alpha_g,
                             const __hip_bfloat16* __restrict__ Psw,
                             const __hip_bfloat16* __restrict__ PmuA,
                             const __hip_bfloat16* __restrict__ PmuB,
                             float* __restrict__ out) {
  __shared__ __attribute__((aligned(16))) char scratch[4 * PW_BYTES];  // 28 KB

  const int tid = threadIdx.x;
  const int wave = tid >> 6, lane = tid & 63;
  const int q = lane >> 4, l4 = lane & 15;
  const int base_pt = blockIdx.x * 128 + wave * 32;
  const float alpha = alpha_g[0];

  char* pw = scratch + wave * PW_BYTES;
  __hip_bfloat16* xsw = (__hip_bfloat16*)pw;           // [32][XROW] bf16 staging
  float* pmxw = (float*)pw;                            // [32][32] f32 (xsw dead)
  __hip_bfloat16* wtw = (__hip_bfloat16*)(pw + 4608);  // [32][WT_PITCH] bf16

  const bf16x8* PswF = (const bf16x8*)Psw;    // frag idx = k*512 + f*64 + lane
  const bf16x8* PmuAF = (const bf16x8*)PmuA;  // frag idx = f*64 + lane
  const bf16x8* PmuBF = (const bf16x8*)PmuB;

  // x master, C-layout: xm[mt][nt][r] = x[dim = mt*16+q*4+r][pt = nt*16+l4]
  f32x4 xm[4][2];
#pragma unroll
  for (int mt = 0; mt < 4; ++mt)
#pragma unroll
    for (int nt = 0; nt < 2; ++nt)
      xm[mt][nt] = *(const f32x4*)&x_in[(base_pt + nt * 16 + l4) * 64 + mt * 16 + q * 4];

  // e for pmx spill: cluster row mtc*16 + q*4 + r  ->  ev[mtc][r]
  f32x4 ev[2];
#pragma unroll
  for (int mtc = 0; mtc < 2; ++mtc) ev[mtc] = *(const f32x4*)&e_g[mtc * 16 + q * 4];

  const f32x4 Z4 = {0.f, 0.f, 0.f, 0.f};

#pragma unroll 1
  for (int it = 0; it < NITER; ++it) {
    // ---- stage x (bf16) into wave-private rows [pt][dim], XROW-padded ----
#pragma unroll
    for (int mt = 0; mt < 4; ++mt)
#pragma unroll
      for (int nt = 0; nt < 2; ++nt) {
        uint2 v;
        v.x = pk_bf16(xm[mt][nt][0], xm[mt][nt][1]);
        v.y = pk_bf16(xm[mt][nt][2], xm[mt][nt][3]);
        *(uint2*)&xsw[(nt * 16 + l4) * XROW + mt * 16 + q * 4] = v;
      }

    // ---- B-frags of x: B[kk=dim=s*32+q*8+j][n=pt=l4] (constant over k) ----
    bf16x8 bx[2][2];
#pragma unroll
    for (int s = 0; s < 2; ++s)
#pragma unroll
      for (int nt = 0; nt < 2; ++nt)
        bx[s][nt] = *(const bf16x8*)&xsw[(nt * 16 + l4) * XROW + s * 32 + q * 8];

    // ---- preload P(k=0) fragments into register buffer 0 ----
    bf16x8 ap[2][4][2];
#pragma unroll
    for (int mt = 0; mt < 4; ++mt)
#pragma unroll
      for (int s = 0; s < 2; ++s)
        ap[0][mt][s] = PswF[(mt * 2 + s) * 64 + lane];

    // ---- pmx GEMM (s-outer: independent MFMAs first, then dependents) ----
    f32x4 pmx[2][2];
#pragma unroll
    for (int mtc = 0; mtc < 2; ++mtc)
#pragma unroll
      for (int nt = 0; nt < 2; ++nt)
        pmx[mtc][nt] =
            __builtin_amdgcn_mfma_f32_16x16x32_bf16(PmuAF[(mtc * 2) * 64 + lane], bx[0][nt], Z4, 0, 0, 0);
#pragma unroll
    for (int mtc = 0; mtc < 2; ++mtc)
#pragma unroll
      for (int nt = 0; nt < 2; ++nt)
        pmx[mtc][nt] = __builtin_amdgcn_mfma_f32_16x16x32_bf16(PmuAF[(mtc * 2 + 1) * 64 + lane],
                                                               bx[1][nt], pmx[mtc][nt], 0, 0, 0);
    // spill pmx + e (folded) to wave-private LDS [cluster32][pt32] f32
#pragma unroll
    for (int mtc = 0; mtc < 2; ++mtc)
#pragma unroll
      for (int nt = 0; nt < 2; ++nt)
#pragma unroll
        for (int r = 0; r < 4; ++r)
          pmxw[(mtc * 16 + q * 4 + r) * 32 + nt * 16 + l4] = pmx[mtc][nt][r] + ev[mtc][r];

    f32x4 accY[4][2];
#pragma unroll
    for (int mt = 0; mt < 4; ++mt)
#pragma unroll
      for (int nt = 0; nt < 2; ++nt) accY[mt][nt] = Z4;
    float lsum0 = 0.f, lsum1 = 0.f;

    // ---- k-loop: register-double-buffered P, no barriers ----
#pragma unroll 2
    for (int k = 0; k < KC; ++k) {
      const int cur = k & 1, nxt = cur ^ 1;
      const int kn = (k + 1) & (KC - 1);  // wraps to 0 on last step (harmless)
#pragma unroll
      for (int mt = 0; mt < 4; ++mt)
#pragma unroll
        for (int s = 0; s < 2; ++s)
          ap[nxt][mt][s] = PswF[kn * 512 + (mt * 2 + s) * 64 + lane];

      // y = P x, s-outer emission: 8 independent s=0 MFMAs issue back-to-back,
      // then the 8 s=1 MFMAs (each sees its s=0 result ~8 issues later ->
      // MFMA latency hidden instead of stalling in-order issue per pair)
      f32x4 y[4][2];
#pragma unroll
      for (int mt = 0; mt < 4; ++mt)
#pragma unroll
        for (int nt = 0; nt < 2; ++nt)
          y[mt][nt] = __builtin_amdgcn_mfma_f32_16x16x32_bf16(ap[cur][mt][0], bx[0][nt], Z4, 0, 0, 0);
#pragma unroll
      for (int mt = 0; mt < 4; ++mt)
#pragma unroll
        for (int nt = 0; nt < 2; ++nt)
          y[mt][nt] =
              __builtin_amdgcn_mfma_f32_16x16x32_bf16(ap[cur][mt][1], bx[1][nt], y[mt][nt], 0, 0, 0);

      // xy[pt] = x . y : packed fp32 FMAs, chain depth 4
      f32x4 d0 = xm[0][0] * y[0][0];
      f32x4 d1 = xm[0][1] * y[0][1];
#pragma unroll
      for (int mt = 1; mt < 4; ++mt) {
        d0 += xm[mt][0] * y[mt][0];
        d1 += xm[mt][1] * y[mt][1];
      }
      float xy0 = (d0[0] + d0[1]) + (d0[2] + d0[3]);
      float xy1 = (d1[0] + d1[1]) + (d1[2] + d1[3]);
      xy0 = red32(red16(xy0));
      xy1 = red32(red16(xy1));

      const float pk0 = pmxw[k * 32 + l4];       // includes e_k
      const float pk1 = pmxw[k * 32 + 16 + l4];
      const float w0 = __expf(pk0 - 0.5f * xy0);
      const float w1 = __expf(pk1 - 0.5f * xy1);
      lsum0 += w0;
      lsum1 += w1;
      if (q == 0) {
        wtw[l4 * WT_PITCH + k] = __float2bfloat16(w0);
        wtw[(16 + l4) * WT_PITCH + k] = __float2bfloat16(w1);
      }
      // accY += w * y (packed fp32 FMA)
#pragma unroll
      for (int mt = 0; mt < 4; ++mt) {
        accY[mt][0] += w0 * y[mt][0];
        accY[mt][1] += w1 * y[mt][1];
      }
    }

    // ---- pacc[dim][pt] = sum_k Pmu[k][dim] * wt[k][pt]  (one K=32 GEMM) ----
    bf16x8 wtf[2];
#pragma unroll
    for (int nt = 0; nt < 2; ++nt)
      wtf[nt] = *(const bf16x8*)&wtw[(nt * 16 + l4) * WT_PITCH + q * 8];
    f32x4 pacc[4][2];
#pragma unroll
    for (int mt = 0; mt < 4; ++mt) {
      bf16x8 a = PmuBF[mt * 64 + lane];
      pacc[mt][0] = __builtin_amdgcn_mfma_f32_16x16x32_bf16(a, wtf[0], Z4, 0, 0, 0);
      pacc[mt][1] = __builtin_amdgcn_mfma_f32_16x16x32_bf16(a, wtf[1], Z4, 0, 0, 0);
    }

    // ---- x += (alpha/l) * (pacc - accY) ----
    const float c0 = alpha / lsum0;
    const float c1 = alpha / lsum1;
#pragma unroll
    for (int mt = 0; mt < 4; ++mt) {
      xm[mt][0] += c0 * (pacc[mt][0] - accY[mt][0]);
      xm[mt][1] += c1 * (pacc[mt][1] - accY[mt][1]);
    }
  }  // iterations

  // ---- direct f32x4 stores: 64B-contiguous per quad-row, fully in-bounds ---
#pragma unroll
  for (int mt = 0; mt < 4; ++mt)
#pragma unroll
    for (int nt = 0; nt < 2; ++nt)
      *(f32x4*)&out[(base_pt + nt * 16 + l4) * 64 + mt * 16 + q * 4] = xm[mt][nt];
}

extern "C" void kernel_launch(void* const* d_in, const int* in_sizes, int n_in,
                              void* d_out, int out_size, void* d_ws, size_t ws_size,
                              hipStream_t stream) {
  (void)in_sizes; (void)n_in; (void)out_size; (void)ws_size;
  const float* x = (const float*)d_in[0];
  const float* c = (const float*)d_in[1];
  const float* mu = (const float*)d_in[2];
  const float* A = (const float*)d_in[3];
  const float* alpha = (const float*)d_in[4];
  float* out = (float*)d_out;

  char* ws = (char*)d_ws;
  float* Pmu_g = (float*)(ws);                           // 8192 B
  float* e_g = (float*)(ws + 8192);                      // 128 B (pad to 256)
  __hip_bfloat16* PmuA = (__hip_bfloat16*)(ws + 8448);   // 4096 B
  __hip_bfloat16* PmuB = (__hip_bfloat16*)(ws + 12544);  // 4096 B
  __hip_bfloat16* Psw = (__hip_bfloat16*)(ws + 16640);   // 262144 B

  precompute1<<<32, 256, 0, stream>>>(A, mu, c, Pmu_g, e_g, Psw);
  precompute2<<<1, 256, 0, stream>>>(Pmu_g, PmuA, PmuB);
  denoise_main<<<512, 256, 0, stream>>>(x, e_g, alpha, Psw, PmuA, PmuB, out);
}